// Round 2
// baseline (954.429 us; speedup 1.0000x reference)
//
#include <hip/hip_runtime.h>

typedef unsigned short u16;
typedef float f32x4 __attribute__((ext_vector_type(4)));
typedef short bf16x8 __attribute__((ext_vector_type(8)));
typedef u16 u16x8 __attribute__((ext_vector_type(8)));

#define HID 4096
#define SEQ 2048
#define LDQKV 6144

__device__ __forceinline__ u16 f2b(float f) {
    union { float f; unsigned u; } v; v.f = f;
    unsigned r = v.u + 0x7FFFu + ((v.u >> 16) & 1u);
    return (u16)(r >> 16);
}
__device__ __forceinline__ float b2f(u16 u) {
    union { unsigned u; float f; } v; v.u = ((unsigned)u) << 16;
    return v.f;
}
__device__ __forceinline__ f32x4 mfma16(bf16x8 a, bf16x8 b, f32x4 c) {
    return __builtin_amdgcn_mfma_f32_16x16x32_bf16(a, b, c, 0, 0, 0);
}
__device__ __forceinline__ void gload16(const void* g, void* l) {
    __builtin_amdgcn_global_load_lds(
        (const __attribute__((address_space(1))) unsigned int*)g,
        (__attribute__((address_space(3))) unsigned int*)l,
        16, 0, 0);
}

// ---------------- fp32 -> bf16 elementwise (X) ----------------
__global__ void k_cvt_bf16(const float* __restrict__ x, u16* __restrict__ y) {
    int i = blockIdx.x * 256 + threadIdx.x;   // each thread: 8 elems
    const f32x4* p = (const f32x4*)(x + (size_t)i * 8);
    f32x4 a = p[0], b = p[1];
    u16x8 o;
    o[0]=f2b(a.x); o[1]=f2b(a.y); o[2]=f2b(a.z); o[3]=f2b(a.w);
    o[4]=f2b(b.x); o[5]=f2b(b.y); o[6]=f2b(b.z); o[7]=f2b(b.w);
    *(u16x8*)(y + (size_t)i * 8) = o;
}

// ------------- transpose + convert weights: W (K x N) fp32 -> WT (N x K=4096) bf16 -------------
__global__ void k_twc(const float* __restrict__ W, int N, u16* __restrict__ WT) {
    __shared__ float tile[64][68];
    int t = threadIdx.x;
    int n0 = blockIdx.x * 64, k0 = blockIdx.y * 64;
#pragma unroll
    for (int i = 0; i < 4; i++) {
        int idx = i * 256 + t;
        int r = idx >> 4;
        int c = (idx & 15) * 4;
        f32x4 v = *(const f32x4*)(W + (size_t)(k0 + r) * N + n0 + c);
        tile[r][c] = v.x; tile[r][c+1] = v.y; tile[r][c+2] = v.z; tile[r][c+3] = v.w;
    }
    __syncthreads();
    int n_l = t >> 2;
    int c0 = (t & 3) * 16;
    u16x8 o0, o1;
#pragma unroll
    for (int u = 0; u < 8; u++) {
        o0[u] = f2b(tile[c0 + u][n_l]);
        o1[u] = f2b(tile[c0 + 8 + u][n_l]);
    }
    u16* dst = WT + (size_t)(n0 + n_l) * 4096 + k0 + c0;
    *(u16x8*)dst = o0;
    *(u16x8*)(dst + 8) = o1;
}

// ---------------- RoPE cos/sin table: rows = B*S (position = row & 2047), 64 freqs ----------------
__global__ void k_rope_tab(float* __restrict__ ct, float* __restrict__ st) {
    int idx = blockIdx.x * 256 + threadIdx.x;   // < 4096*64
    int row = idx >> 6, i = idx & 63;
    float p = (float)(row & (SEQ - 1));
    // inv_freq = 500000^(-i/64) = exp2(-i * log2(500000)/64)
    float inv = exp2f(-(float)i * 0.29582835f);
    float f = p * inv;
    ct[idx] = cosf(f);
    st[idx] = sinf(f);
}

// ---------------- RoPE apply in-place on Q (cols 0..4095) and K (cols 4096..5119) ----------------
__global__ void k_rope(u16* __restrict__ qkv, const float* __restrict__ ct, const float* __restrict__ st) {
    int t = threadIdx.x, w = t >> 6, lane = t & 63;
    int hr = blockIdx.x * 4 + w;      // head-row id < 4096*40
    int row = hr / 40, hh = hr % 40;
    int col0 = (hh < 32) ? hh * 128 : 4096 + (hh - 32) * 128;
    u16* p = qkv + (size_t)row * LDQKV + col0;
    float c = ct[row * 64 + lane], s = st[row * 64 + lane];
    float x1 = b2f(p[lane]), x2 = b2f(p[lane + 64]);
    p[lane]      = f2b(x1 * c - x2 * s);
    p[lane + 64] = f2b(x2 * c + x1 * s);
}

// ---------------- GEMM: C(MxN) = A(MxK) * Bt(NxK)^T, bf16 in, 128x128 tile, BK=64 ----------------
// MODE 0: bf16 out with V-split (cols >= 5120 go transposed into Vt);  MODE 1: fp32 out
template <int MODE>
__global__ __launch_bounds__(256) void k_gemm(const u16* __restrict__ A, const u16* __restrict__ Bt,
                                              void* __restrict__ C, u16* __restrict__ Vt,
                                              int K, int ldc) {
    __shared__ __align__(16) u16 Al[128 * 64];
    __shared__ __align__(16) u16 Bl[128 * 64];
    int t = threadIdx.x, w = t >> 6, lane = t & 63;
    int lr = lane & 15, lg = lane >> 4;
    int wr = w >> 1, wc = w & 1;
    int by = blockIdx.y, bx = blockIdx.x;

    const char* gA[4]; const char* gB[4];
    char* lA[4]; char* lB[4];
#pragma unroll
    for (int i = 0; i < 4; i++) {
        int o = i * 4096 + w * 1024 + lane * 16;
        int r = o >> 7, cb = o & 127;
        int scb = cb ^ ((r & 7) << 4);           // pre-swizzled global source
        gA[i] = (const char*)A + (size_t)(by * 128 + r) * K * 2 + scb;
        gB[i] = (const char*)Bt + (size_t)(bx * 128 + r) * K * 2 + scb;
        lA[i] = (char*)Al + i * 4096 + w * 1024; // wave-uniform linear LDS dest
        lB[i] = (char*)Bl + i * 4096 + w * 1024;
    }

    f32x4 acc[4][4] = {};
    int nk = K >> 6;
    for (int kt = 0; kt < nk; kt++) {
#pragma unroll
        for (int i = 0; i < 4; i++) gload16(gA[i], lA[i]);
#pragma unroll
        for (int i = 0; i < 4; i++) gload16(gB[i], lB[i]);
#pragma unroll
        for (int i = 0; i < 4; i++) { gA[i] += 128; gB[i] += 128; }
        __syncthreads();
#pragma unroll
        for (int kk = 0; kk < 2; kk++) {
            bf16x8 af[4], bfr[4];
#pragma unroll
            for (int m = 0; m < 4; m++) {
                int row = wr * 64 + m * 16 + lr;
                af[m] = *(const bf16x8*)((const char*)Al + row * 128 + ((kk * 64 + lg * 16) ^ ((row & 7) << 4)));
            }
#pragma unroll
            for (int n = 0; n < 4; n++) {
                int row = wc * 64 + n * 16 + lr;
                bfr[n] = *(const bf16x8*)((const char*)Bl + row * 128 + ((kk * 64 + lg * 16) ^ ((row & 7) << 4)));
            }
#pragma unroll
            for (int m = 0; m < 4; m++)
#pragma unroll
                for (int n = 0; n < 4; n++)
                    acc[m][n] = mfma16(af[m], bfr[n], acc[m][n]);
        }
        __syncthreads();
    }

    int rowBase = by * 128 + wr * 64;
    int colBase = bx * 128 + wc * 64;
    if (MODE == 0) {
        bool isV = (colBase >= 5120);
        if (!isV) {
            u16* Cb = (u16*)C;
#pragma unroll
            for (int m = 0; m < 4; m++)
#pragma unroll
                for (int n = 0; n < 4; n++)
#pragma unroll
                    for (int j = 0; j < 4; j++) {
                        int grow = rowBase + m * 16 + lg * 4 + j;
                        int gcol = colBase + n * 16 + lr;
                        Cb[(size_t)grow * ldc + gcol] = f2b(acc[m][n][j]);
                    }
        } else {
#pragma unroll
            for (int m = 0; m < 4; m++)
#pragma unroll
                for (int n = 0; n < 4; n++)
#pragma unroll
                    for (int j = 0; j < 4; j++) {
                        int grow = rowBase + m * 16 + lg * 4 + j;
                        int gcol = colBase + n * 16 + lr;
                        int cv = gcol - 5120;
                        int kvh = cv >> 7, d = cv & 127;
                        int b = grow >> 11, s2 = grow & 2047;
                        Vt[(size_t)((b * 8 + kvh) * 128 + d) * 2048 + s2] = f2b(acc[m][n][j]);
                    }
        }
    } else {
        float* Cf = (float*)C;
#pragma unroll
        for (int m = 0; m < 4; m++)
#pragma unroll
            for (int n = 0; n < 4; n++)
#pragma unroll
                for (int j = 0; j < 4; j++) {
                    int grow = rowBase + m * 16 + lg * 4 + j;
                    int gcol = colBase + n * 16 + lr;
                    Cf[(size_t)grow * ldc + gcol] = acc[m][n][j];
                }
    }
}

// ---------------- Flash attention: QBLK=64 (16 rows/wave), KVBLK=64, causal, GQA 4:1 ----------------
__global__ __launch_bounds__(256) void k_attn(const u16* __restrict__ qkv, const u16* __restrict__ Vt,
                                              u16* __restrict__ out) {
    __shared__ __align__(16) u16 Kl[64 * 128];
    __shared__ __align__(16) u16 Vl[128 * 64];
    __shared__ __align__(16) u16 Pl[4 * 16 * 72];
    int t = threadIdx.x, w = t >> 6, lane = t & 63;
    int lr = lane & 15, lg = lane >> 4;
    int qt = blockIdx.x, h = blockIdx.y, b = blockIdx.z;
    int kvh = h >> 2;
    int q0 = qt * 64;

    bf16x8 qf[4];
    {
        int qrow = q0 + w * 16 + lr;
        const u16* qp = qkv + (size_t)(b * SEQ + qrow) * LDQKV + h * 128 + lg * 8;
#pragma unroll
        for (int kd = 0; kd < 4; kd++) qf[kd] = *(const bf16x8*)(qp + kd * 32);
    }

    f32x4 acc[8] = {};
    float m_r[4], l_r[4];
#pragma unroll
    for (int j = 0; j < 4; j++) { m_r[j] = -INFINITY; l_r[j] = 0.f; }
    const float scale = 0.08838834764831845f;

    const char* Kbase = (const char*)qkv + (size_t)b * SEQ * (LDQKV * 2) + (size_t)(4096 + kvh * 128) * 2;
    const char* Vbase = (const char*)Vt + (size_t)(b * 8 + kvh) * 128 * 4096;
    u16* Pw = Pl + w * 16 * 72;

    for (int kv = 0; kv <= qt; kv++) {
        int kv0 = kv * 64;
        // stage K [64][128] and Vt [128][64], source-XOR-swizzled
#pragma unroll
        for (int i = 0; i < 4; i++) {
            int o = i * 4096 + w * 1024 + lane * 16;
            {
                int sk = o >> 8, cb = o & 255;
                int scb = cb ^ ((sk & 7) << 4);
                gload16(Kbase + (size_t)(kv0 + sk) * (LDQKV * 2) + scb, (char*)Kl + i * 4096 + w * 1024);
            }
            {
                int d = o >> 7, cb = o & 127;
                int scb = cb ^ ((d & 7) << 4);
                gload16(Vbase + (size_t)d * 4096 + kv0 * 2 + scb, (char*)Vl + i * 4096 + w * 1024);
            }
        }
        __syncthreads();

        // QK^T: S (16 q x 64 k) per wave
        f32x4 sf[4];
#pragma unroll
        for (int f = 0; f < 4; f++) {
            f32x4 s = {};
            int skr = f * 16 + lr;
            const char* kr = (const char*)Kl + skr * 256;
            int sw = (skr & 7) << 4;
#pragma unroll
            for (int kd = 0; kd < 4; kd++) {
                bf16x8 kb = *(const bf16x8*)(kr + ((kd * 64 + lg * 16) ^ sw));
                s = mfma16(qf[kd], kb, s);
            }
            sf[f] = s;
        }

        // online softmax (fp32)
        int qrow_g = q0 + w * 16 + lg * 4;
        float mnew[4], alpha[4];
#pragma unroll
        for (int j = 0; j < 4; j++) {
            float mx = -INFINITY;
#pragma unroll
            for (int f = 0; f < 4; f++) {
                float v = sf[f][j] * scale;
                int colg = kv0 + f * 16 + lr;
                if (colg > qrow_g + j) v = -INFINITY;
                sf[f][j] = v;
                mx = fmaxf(mx, v);
            }
#pragma unroll
            for (int d = 1; d < 16; d <<= 1) mx = fmaxf(mx, __shfl_xor(mx, d));
            mnew[j] = fmaxf(m_r[j], mx);
            alpha[j] = __expf(m_r[j] - mnew[j]);
            m_r[j] = mnew[j];
        }
#pragma unroll
        for (int j = 0; j < 4; j++) {
            float sum = 0.f;
#pragma unroll
            for (int f = 0; f < 4; f++) {
                float p = __expf(sf[f][j] - mnew[j]);
                sf[f][j] = p;
                sum += p;
            }
#pragma unroll
            for (int d = 1; d < 16; d <<= 1) sum += __shfl_xor(sum, d);
            l_r[j] = l_r[j] * alpha[j] + sum;
        }
#pragma unroll
        for (int nf = 0; nf < 8; nf++)
#pragma unroll
            for (int j = 0; j < 4; j++) acc[nf][j] *= alpha[j];

        // P -> LDS (bf16), wave-private padded tile [16][72]
#pragma unroll
        for (int f = 0; f < 4; f++)
#pragma unroll
            for (int j = 0; j < 4; j++)
                Pw[(lg * 4 + j) * 72 + f * 16 + lr] = f2b(sf[f][j]);

        // PV
        bf16x8 pa[2];
#pragma unroll
        for (int kk = 0; kk < 2; kk++)
            pa[kk] = *(const bf16x8*)(Pw + lr * 72 + kk * 32 + lg * 8);
#pragma unroll
        for (int nf = 0; nf < 8; nf++) {
            int d = nf * 16 + lr;
            const char* vr = (const char*)Vl + d * 128;
            int swv = (d & 7) << 4;
#pragma unroll
            for (int kk = 0; kk < 2; kk++) {
                bf16x8 vb = *(const bf16x8*)(vr + ((kk * 64 + lg * 16) ^ swv));
                acc[nf] = mfma16(pa[kk], vb, acc[nf]);
            }
        }
        __syncthreads();
    }

    // epilogue: out = acc / l
#pragma unroll
    for (int nf = 0; nf < 8; nf++)
#pragma unroll
        for (int j = 0; j < 4; j++) {
            float v = acc[nf][j] / l_r[j];
            int qrow = q0 + w * 16 + lg * 4 + j;
            out[(size_t)(b * SEQ + qrow) * 4096 + h * 128 + nf * 16 + lr] = f2b(v);
        }
}

extern "C" void kernel_launch(void* const* d_in, const int* in_sizes, int n_in,
                              void* d_out, int out_size, void* d_ws, size_t ws_size,
                              hipStream_t stream) {
    const float* hs  = (const float*)d_in[0];
    const float* wq  = (const float*)d_in[2];
    const float* wk  = (const float*)d_in[3];
    const float* wv  = (const float*)d_in[4];
    const float* wo  = (const float*)d_in[5];
    float* out = (float*)d_out;
    char* ws = (char*)d_ws;

    // layout (170 MiB total):
    u16* Xb   = (u16*)(ws);                       // 32 MiB  (4096x4096 bf16) — reused as AO after QKV GEMM
    u16* Wt   = (u16*)(ws + 33554432);            // 48 MiB  (6144x4096 bf16, qkv^T concat)
    u16* WoT  = (u16*)(ws + 83886080);            // 32 MiB  (4096x4096 bf16)
    u16* QKV  = (u16*)(ws + 117440512);           // 48 MiB  (4096x6144 bf16; V cols unused)
    u16* Vt   = (u16*)(ws + 167772160);           // 8 MiB   (2*8*128*2048 bf16)
    float* ct = (float*)(ws + 176160768);         // 1 MiB
    float* st = (float*)(ws + 177209344);         // 1 MiB
    u16* AO   = Xb;                               // alias: attention output

    k_cvt_bf16<<<8192, 256, 0, stream>>>(hs, Xb);
    k_twc<<<dim3(64, 64), 256, 0, stream>>>(wq, 4096, Wt);
    k_twc<<<dim3(16, 64), 256, 0, stream>>>(wk, 1024, Wt + (size_t)4096 * 4096);
    k_twc<<<dim3(16, 64), 256, 0, stream>>>(wv, 1024, Wt + (size_t)5120 * 4096);
    k_twc<<<dim3(64, 64), 256, 0, stream>>>(wo, 4096, WoT);
    k_rope_tab<<<1024, 256, 0, stream>>>(ct, st);
    k_gemm<0><<<dim3(48, 32), 256, 0, stream>>>(Xb, Wt, QKV, Vt, 4096, LDQKV);
    k_rope<<<40960, 256, 0, stream>>>(QKV, ct, st);
    k_attn<<<dim3(32, 32, 2), 256, 0, stream>>>(QKV, Vt, AO);
    k_gemm<1><<<dim3(32, 32), 256, 0, stream>>>(AO, WoT, out, nullptr, 4096, 4096);
}

// Round 3
// 856.293 us; speedup vs baseline: 1.1146x; 1.1146x over previous
//
#include <hip/hip_runtime.h>

typedef unsigned short u16;
typedef float f32x4 __attribute__((ext_vector_type(4)));
typedef short bf16x8 __attribute__((ext_vector_type(8)));
typedef u16 u16x8 __attribute__((ext_vector_type(8)));

#define HID 4096
#define SEQ 2048
#define LDQKV 6144

__device__ __forceinline__ u16 f2b(float f) {
    union { float f; unsigned u; } v; v.f = f;
    unsigned r = v.u + 0x7FFFu + ((v.u >> 16) & 1u);
    return (u16)(r >> 16);
}
__device__ __forceinline__ float b2f(u16 u) {
    union { unsigned u; float f; } v; v.u = ((unsigned)u) << 16;
    return v.f;
}
__device__ __forceinline__ f32x4 mfma16(bf16x8 a, bf16x8 b, f32x4 c) {
    return __builtin_amdgcn_mfma_f32_16x16x32_bf16(a, b, c, 0, 0, 0);
}
__device__ __forceinline__ void gload16(const void* g, void* l) {
    __builtin_amdgcn_global_load_lds(
        (const __attribute__((address_space(1))) unsigned int*)g,
        (__attribute__((address_space(3))) unsigned int*)l,
        16, 0, 0);
}

// ---------------- fp32 -> bf16 elementwise (X) ----------------
__global__ void k_cvt_bf16(const float* __restrict__ x, u16* __restrict__ y) {
    int i = blockIdx.x * 256 + threadIdx.x;   // each thread: 8 elems
    const f32x4* p = (const f32x4*)(x + (size_t)i * 8);
    f32x4 a = p[0], b = p[1];
    u16x8 o;
    o[0]=f2b(a.x); o[1]=f2b(a.y); o[2]=f2b(a.z); o[3]=f2b(a.w);
    o[4]=f2b(b.x); o[5]=f2b(b.y); o[6]=f2b(b.z); o[7]=f2b(b.w);
    *(u16x8*)(y + (size_t)i * 8) = o;
}

// ------------- transpose + convert weights: W (K x N) fp32 -> WT (N x K=4096) bf16 -------------
__global__ void k_twc(const float* __restrict__ W, int N, u16* __restrict__ WT) {
    __shared__ float tile[64][68];
    int t = threadIdx.x;
    int n0 = blockIdx.x * 64, k0 = blockIdx.y * 64;
#pragma unroll
    for (int i = 0; i < 4; i++) {
        int idx = i * 256 + t;
        int r = idx >> 4;
        int c = (idx & 15) * 4;
        f32x4 v = *(const f32x4*)(W + (size_t)(k0 + r) * N + n0 + c);
        tile[r][c] = v.x; tile[r][c+1] = v.y; tile[r][c+2] = v.z; tile[r][c+3] = v.w;
    }
    __syncthreads();
    int n_l = t >> 2;
    int c0 = (t & 3) * 16;
    u16x8 o0, o1;
#pragma unroll
    for (int u = 0; u < 8; u++) {
        o0[u] = f2b(tile[c0 + u][n_l]);
        o1[u] = f2b(tile[c0 + 8 + u][n_l]);
    }
    u16* dst = WT + (size_t)(n0 + n_l) * 4096 + k0 + c0;
    *(u16x8*)dst = o0;
    *(u16x8*)(dst + 8) = o1;
}

// ---------------- RoPE cos/sin table: rows = B*S (position = row & 2047), 64 freqs ----------------
__global__ void k_rope_tab(float* __restrict__ ct, float* __restrict__ st) {
    int idx = blockIdx.x * 256 + threadIdx.x;   // < 4096*64
    int row = idx >> 6, i = idx & 63;
    float p = (float)(row & (SEQ - 1));
    float inv = exp2f(-(float)i * 0.29582835f);
    float f = p * inv;
    ct[idx] = cosf(f);
    st[idx] = sinf(f);
}

// ---------------- RoPE apply in-place on Q (cols 0..4095) and K (cols 4096..5119) ----------------
__global__ void k_rope(u16* __restrict__ qkv, const float* __restrict__ ct, const float* __restrict__ st) {
    int t = threadIdx.x, w = t >> 6, lane = t & 63;
    int hr = blockIdx.x * 4 + w;      // head-row id < 4096*40
    int row = hr / 40, hh = hr % 40;
    int col0 = (hh < 32) ? hh * 128 : 4096 + (hh - 32) * 128;
    u16* p = qkv + (size_t)row * LDQKV + col0;
    float c = ct[row * 64 + lane], s = st[row * 64 + lane];
    float x1 = b2f(p[lane]), x2 = b2f(p[lane + 64]);
    p[lane]      = f2b(x1 * c - x2 * s);
    p[lane + 64] = f2b(x2 * c + x1 * s);
}

// ---------------- GEMM: C(MxN) = A(MxK) * Bt(NxK)^T, bf16 in, 128x128 tile, BK=64 ----------------
template <int MODE>
__global__ __launch_bounds__(256) void k_gemm(const u16* __restrict__ A, const u16* __restrict__ Bt,
                                              void* __restrict__ C, u16* __restrict__ Vt,
                                              int K, int ldc) {
    __shared__ __align__(16) u16 Al[128 * 64];
    __shared__ __align__(16) u16 Bl[128 * 64];
    int t = threadIdx.x, w = t >> 6, lane = t & 63;
    int lr = lane & 15, lg = lane >> 4;
    int wr = w >> 1, wc = w & 1;
    int by = blockIdx.y, bx = blockIdx.x;

    const char* gA[4]; const char* gB[4];
    char* lA[4]; char* lB[4];
#pragma unroll
    for (int i = 0; i < 4; i++) {
        int o = i * 4096 + w * 1024 + lane * 16;
        int r = o >> 7, cb = o & 127;
        int scb = cb ^ ((r & 7) << 4);
        gA[i] = (const char*)A + (size_t)(by * 128 + r) * K * 2 + scb;
        gB[i] = (const char*)Bt + (size_t)(bx * 128 + r) * K * 2 + scb;
        lA[i] = (char*)Al + i * 4096 + w * 1024;
        lB[i] = (char*)Bl + i * 4096 + w * 1024;
    }

    f32x4 acc[4][4] = {};
    int nk = K >> 6;
    for (int kt = 0; kt < nk; kt++) {
#pragma unroll
        for (int i = 0; i < 4; i++) gload16(gA[i], lA[i]);
#pragma unroll
        for (int i = 0; i < 4; i++) gload16(gB[i], lB[i]);
#pragma unroll
        for (int i = 0; i < 4; i++) { gA[i] += 128; gB[i] += 128; }
        __syncthreads();
#pragma unroll
        for (int kk = 0; kk < 2; kk++) {
            bf16x8 af[4], bfr[4];
#pragma unroll
            for (int m = 0; m < 4; m++) {
                int row = wr * 64 + m * 16 + lr;
                af[m] = *(const bf16x8*)((const char*)Al + row * 128 + ((kk * 64 + lg * 16) ^ ((row & 7) << 4)));
            }
#pragma unroll
            for (int n = 0; n < 4; n++) {
                int row = wc * 64 + n * 16 + lr;
                bfr[n] = *(const bf16x8*)((const char*)Bl + row * 128 + ((kk * 64 + lg * 16) ^ ((row & 7) << 4)));
            }
#pragma unroll
            for (int m = 0; m < 4; m++)
#pragma unroll
                for (int n = 0; n < 4; n++)
                    acc[m][n] = mfma16(af[m], bfr[n], acc[m][n]);
        }
        __syncthreads();
    }

    int rowBase = by * 128 + wr * 64;
    int colBase = bx * 128 + wc * 64;
    if (MODE == 0) {
        bool isV = (colBase >= 5120);
        if (!isV) {
            u16* Cb = (u16*)C;
#pragma unroll
            for (int m = 0; m < 4; m++)
#pragma unroll
                for (int n = 0; n < 4; n++)
#pragma unroll
                    for (int j = 0; j < 4; j++) {
                        int grow = rowBase + m * 16 + lg * 4 + j;
                        int gcol = colBase + n * 16 + lr;
                        Cb[(size_t)grow * ldc + gcol] = f2b(acc[m][n][j]);
                    }
        } else {
#pragma unroll
            for (int m = 0; m < 4; m++)
#pragma unroll
                for (int n = 0; n < 4; n++)
#pragma unroll
                    for (int j = 0; j < 4; j++) {
                        int grow = rowBase + m * 16 + lg * 4 + j;
                        int gcol = colBase + n * 16 + lr;
                        int cv = gcol - 5120;
                        int kvh = cv >> 7, d = cv & 127;
                        int b = grow >> 11, s2 = grow & 2047;
                        Vt[(size_t)((b * 8 + kvh) * 128 + d) * 2048 + s2] = f2b(acc[m][n][j]);
                    }
        }
    } else {
        float* Cf = (float*)C;
#pragma unroll
        for (int m = 0; m < 4; m++)
#pragma unroll
            for (int n = 0; n < 4; n++)
#pragma unroll
                for (int j = 0; j < 4; j++) {
                    int grow = rowBase + m * 16 + lg * 4 + j;
                    int gcol = colBase + n * 16 + lr;
                    Cf[(size_t)grow * ldc + gcol] = acc[m][n][j];
                }
    }
}

// ---------------- Flash attention v2: GQA-shared block, 2-phase pipeline, paired q-tiles ----------------
// Block = (pair p, kvh, b). 4 waves = 4 Q-heads of the KV group; each wave: 32 q-rows.
// K double-buffered in LDS; V single-buffered (issued at iter top, consumed after drain barrier).
__global__ __launch_bounds__(256) void k_attn(const u16* __restrict__ qkv, const u16* __restrict__ Vt,
                                              u16* __restrict__ out) {
    __shared__ __align__(16) u16 Kl[2][64 * 128];
    __shared__ __align__(16) u16 Vl[128 * 64];
    __shared__ __align__(16) u16 Pl[4][32 * 72];
    int t = threadIdx.x, w = t >> 6, lane = t & 63;
    int lr = lane & 15, lg = lane >> 4;
    int p = blockIdx.x;        // 0..31  (pair index)
    int kvh = blockIdx.y;      // 0..7
    int b = blockIdx.z;        // 0..1
    int h = kvh * 4 + w;       // this wave's Q head
    const float scale = 0.08838834764831845f;

    const char* Kbase = (const char*)qkv + (size_t)b * SEQ * (LDQKV * 2) + (size_t)(4096 + kvh * 128) * 2;
    const char* Vbase = (const char*)Vt + (size_t)(b * 8 + kvh) * 128 * 4096;
    u16* Pw = Pl[w];

#pragma unroll 1
    for (int half = 0; half < 2; half++) {
        int qa = half ? (63 - p) : p;   // q-tile of 32 rows
        int q0 = qa * 32;
        int nt = qa / 2 + 1;            // kv tiles of 64

        // Q fragments (global, post-RoPE)
        bf16x8 qf[2][4];
#pragma unroll
        for (int m = 0; m < 2; m++)
#pragma unroll
            for (int kd = 0; kd < 4; kd++)
                qf[m][kd] = *(const bf16x8*)(qkv + (size_t)(b * SEQ + q0 + m * 16 + lr) * LDQKV
                                                  + h * 128 + kd * 32 + lg * 8);

        f32x4 acc[2][8] = {};
        float m_r[2][4], l_r[2][4];
#pragma unroll
        for (int m = 0; m < 2; m++)
#pragma unroll
            for (int j = 0; j < 4; j++) { m_r[m][j] = -INFINITY; l_r[m][j] = 0.f; }

        // prologue: stage K(0) into Kl[0]
#pragma unroll
        for (int i = 0; i < 4; i++) {
            int o = i * 4096 + w * 1024 + lane * 16;
            int sk = o >> 8, cb = o & 255;
            int scb = cb ^ ((sk & 7) << 4);
            gload16(Kbase + (size_t)sk * (LDQKV * 2) + scb, (char*)Kl[0] + i * 4096 + w * 1024);
        }
        __syncthreads();   // drain + barrier

        int cur = 0;
#pragma unroll 1
        for (int kv = 0; kv < nt; kv++) {
            int kv0 = kv * 64;
            // issue V(kv) (needed after this phase) and K(kv+1) (needed next iter)
#pragma unroll
            for (int i = 0; i < 4; i++) {
                int o = i * 4096 + w * 1024 + lane * 16;
                int d = o >> 7, cb = o & 127;
                int scb = cb ^ ((d & 7) << 4);
                gload16(Vbase + (size_t)d * 4096 + (size_t)kv0 * 2 + scb, (char*)Vl + i * 4096 + w * 1024);
            }
            if (kv + 1 < nt) {
#pragma unroll
                for (int i = 0; i < 4; i++) {
                    int o = i * 4096 + w * 1024 + lane * 16;
                    int sk = o >> 8, cb = o & 255;
                    int scb = cb ^ ((sk & 7) << 4);
                    gload16(Kbase + (size_t)(kv0 + 64 + sk) * (LDQKV * 2) + scb,
                            (char*)Kl[cur ^ 1] + i * 4096 + w * 1024);
                }
            }

            // QK^T on Kl[cur]  (2m x 4f x 4kd = 32 MFMA)
            f32x4 sf[2][4] = {};
            const char* Kc = (const char*)Kl[cur];
#pragma unroll
            for (int f = 0; f < 4; f++) {
                int skr = f * 16 + lr;
                const char* kr = Kc + skr * 256;
                int sw = (skr & 7) << 4;
#pragma unroll
                for (int kd = 0; kd < 4; kd++) {
                    bf16x8 kb = *(const bf16x8*)(kr + ((kd * 64 + lg * 16) ^ sw));
#pragma unroll
                    for (int m = 0; m < 2; m++) sf[m][f] = mfma16(qf[m][kd], kb, sf[m][f]);
                }
            }

            // online softmax + P->LDS (wave-private)
#pragma unroll
            for (int m = 0; m < 2; m++) {
                int qrow_g = q0 + m * 16 + lg * 4;
                float mnew[4], alpha[4];
#pragma unroll
                for (int j = 0; j < 4; j++) {
                    float mx = -INFINITY;
#pragma unroll
                    for (int f = 0; f < 4; f++) {
                        float v = sf[m][f][j] * scale;
                        int colg = kv0 + f * 16 + lr;
                        if (colg > qrow_g + j) v = -INFINITY;
                        sf[m][f][j] = v;
                        mx = fmaxf(mx, v);
                    }
#pragma unroll
                    for (int d = 1; d < 16; d <<= 1) mx = fmaxf(mx, __shfl_xor(mx, d));
                    mnew[j] = fmaxf(m_r[m][j], mx);
                    alpha[j] = __expf(m_r[m][j] - mnew[j]);
                    m_r[m][j] = mnew[j];
                }
#pragma unroll
                for (int j = 0; j < 4; j++) {
                    float sum = 0.f;
#pragma unroll
                    for (int f = 0; f < 4; f++) {
                        float pv = __expf(sf[m][f][j] - mnew[j]);
                        sf[m][f][j] = pv;
                        sum += pv;
                    }
#pragma unroll
                    for (int d = 1; d < 16; d <<= 1) sum += __shfl_xor(sum, d);
                    l_r[m][j] = l_r[m][j] * alpha[j] + sum;
                }
#pragma unroll
                for (int nf = 0; nf < 8; nf++)
#pragma unroll
                    for (int j = 0; j < 4; j++) acc[m][nf][j] *= alpha[j];
#pragma unroll
                for (int f = 0; f < 4; f++)
#pragma unroll
                    for (int j = 0; j < 4; j++)
                        Pw[(m * 16 + lg * 4 + j) * 72 + f * 16 + lr] = f2b(sf[m][f][j]);
            }

            __syncthreads();   // drain vmcnt (V ready, next-K in flight done too) + all waves staged

            // PV on Vl  (2m x 8nf x 2kk = 32 MFMA)
            bf16x8 pa[2][2];
#pragma unroll
            for (int m = 0; m < 2; m++)
#pragma unroll
                for (int kk = 0; kk < 2; kk++)
                    pa[m][kk] = *(const bf16x8*)(Pw + (m * 16 + lr) * 72 + kk * 32 + lg * 8);
#pragma unroll
            for (int nf = 0; nf < 8; nf++) {
                int d = nf * 16 + lr;
                const char* vr = (const char*)Vl + d * 128;
                int swv = (d & 7) << 4;
#pragma unroll
                for (int kk = 0; kk < 2; kk++) {
                    bf16x8 vb = *(const bf16x8*)(vr + ((kk * 64 + lg * 16) ^ swv));
#pragma unroll
                    for (int m = 0; m < 2; m++) acc[m][nf] = mfma16(pa[m][kk], vb, acc[m][nf]);
                }
            }
            __syncthreads();   // protect Vl/Kl before next iteration's staging
            cur ^= 1;
        }

        // epilogue
#pragma unroll
        for (int m = 0; m < 2; m++)
#pragma unroll
            for (int nf = 0; nf < 8; nf++)
#pragma unroll
                for (int j = 0; j < 4; j++) {
                    int qrow = q0 + m * 16 + lg * 4 + j;
                    out[(size_t)(b * SEQ + qrow) * 4096 + h * 128 + nf * 16 + lr]
                        = f2b(acc[m][nf][j] / l_r[m][j]);
                }
    }
}

extern "C" void kernel_launch(void* const* d_in, const int* in_sizes, int n_in,
                              void* d_out, int out_size, void* d_ws, size_t ws_size,
                              hipStream_t stream) {
    const float* hs  = (const float*)d_in[0];
    const float* wq  = (const float*)d_in[2];
    const float* wk  = (const float*)d_in[3];
    const float* wv  = (const float*)d_in[4];
    const float* wo  = (const float*)d_in[5];
    float* out = (float*)d_out;
    char* ws = (char*)d_ws;

    u16* Xb   = (u16*)(ws);                       // 32 MiB — reused as AO after QKV GEMM
    u16* Wt   = (u16*)(ws + 33554432);            // 48 MiB
    u16* WoT  = (u16*)(ws + 83886080);            // 32 MiB
    u16* QKV  = (u16*)(ws + 117440512);           // 48 MiB
    u16* Vt   = (u16*)(ws + 167772160);           // 8 MiB
    float* ct = (float*)(ws + 176160768);         // 1 MiB
    float* st = (float*)(ws + 177209344);         // 1 MiB
    u16* AO   = Xb;

    k_cvt_bf16<<<8192, 256, 0, stream>>>(hs, Xb);
    k_twc<<<dim3(64, 64), 256, 0, stream>>>(wq, 4096, Wt);
    k_twc<<<dim3(16, 64), 256, 0, stream>>>(wk, 1024, Wt + (size_t)4096 * 4096);
    k_twc<<<dim3(16, 64), 256, 0, stream>>>(wv, 1024, Wt + (size_t)5120 * 4096);
    k_twc<<<dim3(64, 64), 256, 0, stream>>>(wo, 4096, WoT);
    k_rope_tab<<<1024, 256, 0, stream>>>(ct, st);
    k_gemm<0><<<dim3(48, 32), 256, 0, stream>>>(Xb, Wt, QKV, Vt, 4096, LDQKV);
    k_rope<<<40960, 256, 0, stream>>>(QKV, ct, st);
    k_attn<<<dim3(32, 8, 2), 256, 0, stream>>>(QKV, Vt, AO);
    k_gemm<1><<<dim3(32, 32), 256, 0, stream>>>(AO, WoT, out, nullptr, 4096, 4096);
}